// Round 12
// baseline (1542.838 us; speedup 1.0000x reference)
//
#include <hip/hip_runtime.h>

// PRNNLayer: B=4096 chains x T=2048 steps, 5 states.
// R14: R12 role bodies verbatim (pins, packed streams, planes+tx, no
// barriers, no LDS -- R13's split+barriers regressed and is reverted), with
// a WAVE-TOPOLOGY change: 32 blocks x 512 threads, each block = 8 waves of
// the SAME role covering 8 chain-groups. 1 block/CU -> waves go round-robin
// onto the 4 SIMDs = 2 waves/SIMD. Rationale: R8-R13 all land at ~300+
// cyc/step regardless of instruction content -> ~half is exposed dependent
// trans latency (state->ex2->rcp->state) that a lone in-order wave cannot
// hide (R9: compiler won't interleave two chains in one wave). The HW wave
// scheduler interleaves co-resident waves every cycle -- the same overlap,
// done in hardware. Same-role packing keeps the per-CU I$ footprint at one
// role body (preserves R8's win). tx: 8 timesteps/thread (secondary).

#define NB 4096
#define NT 2048
#define CH0 16
#define K1 16
#define CH23 32
#define BT ((size_t)NB * (size_t)NT)

#define L2E10 14.4269504089f  // 10*log2(e)  (hv(x) = sigmoid(10x))
#define L2E    1.44269504089f

__device__ __forceinline__ float rcpf(float x) { return __builtin_amdgcn_rcpf(x); }
__device__ __forceinline__ float ex2(float a)  { return __builtin_amdgcn_exp2f(a); }
__device__ __forceinline__ float ex2c(float a) { return __builtin_amdgcn_exp2f(fminf(a, 80.0f)); }
__device__ __forceinline__ float clip1e5(float x) {
    return __builtin_amdgcn_fmed3f(x, -100000.0f, 100000.0f);
}
// Pin staged float4s into live VGPRs here (prevents load sinking past this).
__device__ __forceinline__ void pinbuf(const float* d, int n4) {
    const float4* v = (const float4*)d;
    #pragma unroll
    for (int i = 0; i < n4; ++i)
        asm volatile("" :: "v"(v[i].x), "v"(v[i].y), "v"(v[i].z), "v"(v[i].w));
}

// ---------------- Pass 0: input-only terms -> packed scratch planes --------
// out[0..4BT): pack1 float4{pe,psnow,dm,mdd}; out[4BT..5BT): p-plane.
// if use_p0: ws[5BT..9BT): pack0 float4{p,kterm,zday,da}.
__global__ __launch_bounds__(256)
void pre_kernel(const float* __restrict__ inp, const float* __restrict__ theta,
                float* __restrict__ out, float* __restrict__ wsp, int use_p0) {
    const float ddf_   = theta[3] * 5.0f;
    const float tmin_  = theta[4] * -3.0f;
    const float tmax_  = theta[5] * 3.0f;
    const float Kc_    = theta[6] * 0.5f;
    const float SCmax_ = theta[7] * 1.5f;
    const float KcDc  = Kc_ * 0.849932f;
    const float c_sn  = -L2E10 * tmin_;
    const float c_m   =  L2E10 * tmax_;
    const float c_dd  = -ddf_ * tmax_;
    const float c_sc1 =  L2E10 * SCmax_ * 1.4f;
    const float c_sc0 =  L2E10 * SCmax_ * 0.6f;

    const size_t k = (size_t)blockIdx.x * 256 + threadIdx.x;  // 4 elems each
    const float4* i4 = (const float4*)(inp + k * 12);
    const float4 A = i4[0], Bv = i4[1], C = i4[2];
    const float P[4] = {A.x, A.w, Bv.z, C.y};
    const float T[4] = {A.y, Bv.x, Bv.w, C.z};
    const float D[4] = {A.z, Bv.y, C.x, C.w};

    float4 pk1[4], pk0[4];
    float pp[4];
    #pragma unroll
    for (int j = 0; j < 4; ++j) {
        const float p = P[j], tm = T[j], dl = D[j];
        const float A1 = tm + 237.3f;
        const float A2 = tm + 273.2f;
        const float q  = rcpf(A1 * A2);
        const float pe = 436.98672f * dl * ex2(24.958624f * tm * (q * A2)) * (q * A1);
        const float psnow = rcpf(1.0f + ex2(fmaf(L2E10, tm, c_sn))) * p;
        const float dm  = 1.0f + ex2(fmaf(-L2E10, tm, c_m));
        const float mdd = fmaf(ddf_, tm, c_dd);
        pk1[j] = make_float4(pe, psnow, dm, mdd);
        pp[j] = p;
        if (use_p0) {
            const float day = rcpf(1.0f + ex2(fmaf(-L2E10, dl, 7.21347520f)));
            const float da  = 1.0f + ex2(fmaf(-L2E10, p, L2E));
            const float lai   = fmaf(0.328f, day, 0.15f);
            const float kcf   = fmaf(0.6f, day, 0.4f);
            const float kterm = KcDc * kcf * lai;
            const float zday  = fmaf(c_sc1, day, c_sc0);
            pk0[j] = make_float4(p, kterm, zday, da);
        }
    }
    float4* o1 = (float4*)out + k * 4;
    #pragma unroll
    for (int j = 0; j < 4; ++j) o1[j] = pk1[j];
    *(float4*)(out + 4 * BT + k * 4) = make_float4(pp[0], pp[1], pp[2], pp[3]);
    if (use_p0) {
        float4* o0 = (float4*)(wsp + 5 * BT) + k * 4;
        #pragma unroll
        for (int j = 0; j < 4; ++j) o0[j] = pk0[j];
    }
}

// ---------------- Pass 1: role-decomposed serial scans ----------------------
// 32 blocks x 512 threads. Block role = blockIdx&3; 8 waves = 8 chain-groups.
__global__ __launch_bounds__(512, 1)
void prnn_roles(const float* __restrict__ inp, const float* __restrict__ theta,
                float* __restrict__ out, float* __restrict__ wsp,
                int use_ws, int use_p0) {
    const int lane = threadIdx.x & 63;
    const int wave = threadIdx.x >> 6;
    const int role = blockIdx.x & 3;
    const int b = ((blockIdx.x >> 2) * 8 + wave) * 64 + lane;

    const float f_     = theta[0] * 0.1f;
    const float smax_  = theta[1] * 1950.0f;
    const float qmax_  = theta[2] * 50.0f;
    const float ddf_   = theta[3] * 5.0f;
    const float tmin_  = theta[4] * -3.0f;
    const float tmax_  = theta[5] * 3.0f;
    const float Kc_    = theta[6] * 0.5f;
    const float SCmax_ = theta[7] * 1.5f;
    const float spmax_ = theta[8] * 1950.0f;
    const float qpmax_ = theta[9] * 40.0f;
    const float kp     = theta[10];
    const float sgmax_ = theta[11] * 1950.0f;
    const float qgmax_ = theta[12] * 40.0f;
    const float Kl_    = theta[13] * 0.5f;
    const float Kn_    = theta[14] * 0.5f;

    const float inv_smax = rcpf(smax_);
    const float KcDc  = Kc_ * 0.849932f;
    const float c_sn  = -L2E10 * tmin_;
    const float c_m   =  L2E10 * tmax_;
    const float c_dd  = -ddf_ * tmax_;
    const float c_sc1 =  L2E10 * SCmax_ * 1.4f;
    const float c_sc0 =  L2E10 * SCmax_ * 0.6f;
    const float c_2p  =  L2E10 * spmax_;
    const float c_3s  =  L2E10 * smax_;
    const float c_4s  =  L2E10 * sgmax_;
    const float fE    = f_ * L2E;
    const float c_E2  = -fE * spmax_;
    const float c_E3  = -fE * smax_;
    const float c_E4  = -fE * sgmax_;

    const float* ip = inp + (size_t)b * (NT * 3);
    float*       op = out + (size_t)b * (NT * 5);
    float* wbase = use_ws ? wsp : out;

    auto plane_storeN = [&](float* plane, const float* ob, int off, int n4) {
        float4* d = (float4*)(plane + (size_t)off);
        const float4* s = (const float4*)ob;
        #pragma unroll
        for (int i = 0; i < 8; ++i) { if (i < n4) d[i] = s[i]; }
    };

    if (role == 0) {
        // ---- s0 (verbatim R12) ----
        float s0 = 0.f;
        float* w0 = wbase + 0 * BT + (size_t)b * NT;
        if (use_ws && use_p0) {
            const float4* PK = (const float4*)(wsp + 5 * BT) + (size_t)b * NT;
            float bA[CH0 * 4], bB[CH0 * 4];
            auto pf = [&](float* d, int c) {
                #pragma unroll
                for (int i = 0; i < CH0; ++i)
                    ((float4*)d)[i] = PK[(size_t)c * CH0 + i];
            };
            auto cw = [&](const float* d, int c) {
                float ob[CH0];
                #pragma unroll
                for (int i = 0; i < CH0; ++i) {
                    const float p     = d[i * 4 + 0];
                    const float kterm = d[i * 4 + 1];
                    const float zday  = d[i * 4 + 2];
                    const float da    = d[i * 4 + 3];
                    const float e0  = ex2(-L2E10 * s0);
                    const float esc = ex2(fmaf(-L2E10, s0, zday));
                    const float d0  = 1.0f + e0;
                    const float dsc = 1.0f + esc;
                    const float Rp  = rcpf(da * d0 * dsc);
                    const float pintc = Rp * fmaf(d0 * esc, kterm, p);
                    s0 += clip1e5(pintc);
                    ob[i] = s0;
                }
                plane_storeN(w0, ob, c * CH0, CH0 / 4);
            };
            pf(bA, 0);
            for (int c = 0; c < NT / CH0; c += 2) {
                pf(bB, c + 1);
                pinbuf(bA, CH0);
                cw(bA, c);
                if (c + 2 < NT / CH0) pf(bA, c + 2);
                pinbuf(bB, CH0);
                cw(bB, c + 1);
            }
        } else {
            float bA[CH0 * 3], bB[CH0 * 3];
            auto pf = [&](float* d, int c) {
                const float4* s = (const float4*)(ip + (size_t)c * (CH0 * 3));
                #pragma unroll
                for (int i = 0; i < (CH0 * 3) / 4; ++i) ((float4*)d)[i] = s[i];
            };
            auto cw = [&](const float* d, int c) {
                float ob[CH0];
                #pragma unroll
                for (int i = 0; i < CH0; ++i) {
                    const float p  = d[i * 3 + 0];
                    const float dl = d[i * 3 + 2];
                    const float day = rcpf(1.0f + ex2(fmaf(-L2E10, dl, 7.21347520f)));
                    const float da  = 1.0f + ex2(fmaf(-L2E10, p, L2E));
                    const float lai   = fmaf(0.328f, day, 0.15f);
                    const float kcf   = fmaf(0.6f, day, 0.4f);
                    const float kterm = KcDc * kcf * lai;
                    const float zday  = fmaf(c_sc1, day, c_sc0);
                    const float e0  = ex2(-L2E10 * s0);
                    const float esc = ex2(fmaf(-L2E10, s0, zday));
                    const float d0  = 1.0f + e0;
                    const float dsc = 1.0f + esc;
                    const float Rp  = rcpf(da * d0 * dsc);
                    const float pintc = Rp * fmaf(d0 * esc, kterm, p);
                    s0 += clip1e5(pintc);
                    ob[i] = s0;
                }
                if (use_ws) plane_storeN(w0, ob, c * CH0, CH0 / 4);
                else {
                    #pragma unroll
                    for (int i = 0; i < CH0; ++i) op[(c * CH0 + i) * 5 + 0] = ob[i];
                }
            };
            pf(bA, 0);
            for (int c = 0; c < NT / CH0; c += 2) {
                pf(bB, c + 1);
                pinbuf(bA, (CH0 * 3) / 4);
                cw(bA, c);
                if (c + 2 < NT / CH0) pf(bA, c + 2);
                pinbuf(bB, (CH0 * 3) / 4);
                cw(bB, c + 1);
            }
        }
    } else if (role == 1) {
        // ---- s1 + s3 (verbatim R12, combined single wave) ----
        float s1 = 0.f, s3 = 0.f;
        float* w1 = wbase + 1 * BT + (size_t)b * NT;
        float* w3 = wbase + 3 * BT + (size_t)b * NT;
        if (use_ws) {
            const float4* PK = (const float4*)out + (size_t)b * NT;  // pack1
            const float*  PP = out + 4 * BT + (size_t)b * NT;        // p
            float kA[K1 * 4], kB[K1 * 4], pA[K1], pB[K1];
            float ob1[2 * K1], ob3[2 * K1];
            auto pf = [&](float* kd, float* pd, int c) {
                #pragma unroll
                for (int i = 0; i < K1; ++i)
                    ((float4*)kd)[i] = PK[(size_t)c * K1 + i];
                #pragma unroll
                for (int i = 0; i < K1 / 4; ++i)
                    ((float4*)pd)[i] = *(const float4*)(PP + (size_t)c * K1 + i * 4);
            };
            auto cw = [&](const float* kd, const float* pd, int half) {
                #pragma unroll
                for (int i = 0; i < K1; ++i) {
                    const float pe    = kd[i * 4 + 0];
                    const float psnow = kd[i * 4 + 1];
                    const float dm    = kd[i * 4 + 2];
                    const float mdd   = kd[i * 4 + 3];
                    const float prain = pd[i] - psnow;
                    const float e1 = ex2(-L2E10 * s1);
                    const float melt = rcpf(dm * (1.0f + e1)) * fminf(s1, mdd);
                    const float e3  = ex2(-L2E10 * s3);
                    const float e3s = ex2c(fmaf(-L2E10, s3, c_3s));
                    const float R3  = rcpf((1.0f + e3) * (1.0f + e3s));
                    const float E3  = ex2(fmaf(fE, s3, c_E3));
                    const float t_et = pe * fmaf(e3s * s3, inv_smax, 1.0f);
                    const float t_qs = qmax_ * fmaf(e3s, E3, 1.0f);
                    const float outflux = R3 * (t_et + t_qs + (s3 - smax_));
                    const float ds3 = prain + melt - outflux;
                    s1 += clip1e5(psnow - melt);
                    s3 += clip1e5(ds3);
                    ob1[half * K1 + i] = s1;
                    ob3[half * K1 + i] = s3;
                }
            };
            pf(kA, pA, 0);
            for (int c = 0; c < NT / K1; c += 2) {
                pf(kB, pB, c + 1);
                pinbuf(kA, K1); pinbuf(pA, K1 / 4);
                cw(kA, pA, 0);
                if (c + 2 < NT / K1) pf(kA, pA, c + 2);
                pinbuf(kB, K1); pinbuf(pB, K1 / 4);
                cw(kB, pB, 1);
                plane_storeN(w1, ob1, c * K1, (2 * K1) / 4);
                plane_storeN(w3, ob3, c * K1, (2 * K1) / 4);
            }
        } else {
            float bA[CH0 * 3], bB[CH0 * 3];
            auto pf = [&](float* d, int c) {
                const float4* s = (const float4*)(ip + (size_t)c * (CH0 * 3));
                #pragma unroll
                for (int i = 0; i < (CH0 * 3) / 4; ++i) ((float4*)d)[i] = s[i];
            };
            auto cw = [&](const float* d, int c) {
                #pragma unroll
                for (int i = 0; i < CH0; ++i) {
                    const float p  = d[i * 3 + 0];
                    const float tm = d[i * 3 + 1];
                    const float dl = d[i * 3 + 2];
                    const float A1 = tm + 237.3f;
                    const float A2 = tm + 273.2f;
                    const float qq = rcpf(A1 * A2);
                    const float pe = 436.98672f * dl * ex2(24.958624f * tm * (qq * A2)) * (qq * A1);
                    const float psnow = rcpf(1.0f + ex2(fmaf(L2E10, tm, c_sn))) * p;
                    const float dm = 1.0f + ex2(fmaf(-L2E10, tm, c_m));
                    const float prain = p - psnow;
                    const float e1 = ex2(-L2E10 * s1);
                    const float melt = rcpf(dm * (1.0f + e1))
                                       * fminf(s1, fmaf(ddf_, tm, c_dd));
                    const float e3  = ex2(-L2E10 * s3);
                    const float e3s = ex2c(fmaf(-L2E10, s3, c_3s));
                    const float R3  = rcpf((1.0f + e3) * (1.0f + e3s));
                    const float E3  = ex2(fmaf(fE, s3, c_E3));
                    const float t_et = pe * fmaf(e3s * s3, inv_smax, 1.0f);
                    const float t_qs = qmax_ * fmaf(e3s, E3, 1.0f);
                    const float outflux = R3 * (t_et + t_qs + (s3 - smax_));
                    const float ds3 = prain + melt - outflux;
                    s1 += clip1e5(psnow - melt);
                    s3 += clip1e5(ds3);
                    const int t = c * CH0 + i;
                    op[t * 5 + 1] = s1;
                    op[t * 5 + 3] = s3;
                }
            };
            pf(bA, 0);
            for (int c = 0; c < NT / CH0; c += 2) {
                pf(bB, c + 1);
                pinbuf(bA, (CH0 * 3) / 4);
                cw(bA, c);
                if (c + 2 < NT / CH0) pf(bA, c + 2);
                pinbuf(bB, (CH0 * 3) / 4);
                cw(bB, c + 1);
            }
        }
    } else if (role == 2) {
        // ---- s2 (verbatim R12) ----
        float s2 = 0.f;
        float pA[CH23], pB[CH23];
        float* w2 = wbase + 2 * BT + (size_t)b * NT;
        const float* PP = out + 4 * BT + (size_t)b * NT;
        auto pf = [&](float* P, int c) {
            if (use_ws) {
                #pragma unroll
                for (int i = 0; i < CH23 / 4; ++i)
                    ((float4*)P)[i] = *(const float4*)(PP + (size_t)c * CH23 + i * 4);
            } else {
                #pragma unroll
                for (int i = 0; i < CH23; ++i) P[i] = ip[(c * CH23 + i) * 3 + 0];
            }
        };
        auto cw = [&](const float* P, int c) {
            float ob[CH23];
            #pragma unroll
            for (int i = 0; i < CH23; ++i) {
                const float p = P[i];
                const float e2  = ex2(-L2E10 * s2);
                const float e2p = ex2c(fmaf(-L2E10, s2, c_2p));
                const float R2  = rcpf((1.0f + e2) * (1.0f + e2p));
                const float E2  = ex2(fmaf(fE, s2, c_E2));
                const float qpref = R2 * fmaf(e2p * E2, kp * p, qpmax_);
                s2 += clip1e5(qpref);
                ob[i] = s2;
            }
            if (use_ws) plane_storeN(w2, ob, c * CH23, CH23 / 4);
            else {
                #pragma unroll
                for (int i = 0; i < CH23; ++i) op[(c * CH23 + i) * 5 + 2] = ob[i];
            }
        };
        pf(pA, 0);
        for (int c = 0; c < NT / CH23; c += 2) {
            pf(pB, c + 1);
            pinbuf(pA, CH23 / 4);
            cw(pA, c);
            if (c + 2 < NT / CH23) pf(pA, c + 2);
            pinbuf(pB, CH23 / 4);
            cw(pB, c + 1);
        }
    } else {
        // ---- s4 (verbatim R12) ----
        float s4 = 0.f;
        float pA[CH23], pB[CH23];
        float* w4 = wbase + 4 * BT + (size_t)b * NT;
        const float* PP = out + 4 * BT + (size_t)b * NT;
        auto pf = [&](float* P, int c) {
            if (use_ws) {
                #pragma unroll
                for (int i = 0; i < CH23 / 4; ++i)
                    ((float4*)P)[i] = *(const float4*)(PP + (size_t)c * CH23 + i * 4);
            } else {
                #pragma unroll
                for (int i = 0; i < CH23; ++i) P[i] = ip[(c * CH23 + i) * 3 + 0];
            }
        };
        auto cw = [&](const float* P, int c) {
            float ob[CH23];
            #pragma unroll
            for (int i = 0; i < CH23; ++i) {
                const float p = P[i];
                const float e4  = ex2(-L2E10 * s4);
                const float e4s = ex2c(fmaf(-L2E10, s4, c_4s));
                const float R4  = rcpf((1.0f + e4) * (1.0f + e4s));
                const float E4  = ex2(fmaf(fE, s4, c_E4));
                const float pl  = p * fmaf(p, Kn_, Kl_);
                const float qslow = R4 * fmaf(e4s * E4, pl, qgmax_);
                s4 += clip1e5(qslow);
                ob[i] = s4;
            }
            if (use_ws) plane_storeN(w4, ob, c * CH23, CH23 / 4);
            else {
                #pragma unroll
                for (int i = 0; i < CH23; ++i) op[(c * CH23 + i) * 5 + 4] = ob[i];
            }
        };
        pf(pA, 0);
        for (int c = 0; c < NT / CH23; c += 2) {
            pf(pB, c + 1);
            pinbuf(pA, CH23 / 4);
            cw(pA, c);
            if (c + 2 < NT / CH23) pf(pA, c + 2);
            pinbuf(pB, CH23 / 4);
            cw(pB, c + 1);
        }
    }
}

// ---- Pass 2: SoA planes -> AoS out. 8 timesteps per thread. ----
__global__ __launch_bounds__(256)
void tx_kernel(const float* __restrict__ wsp, float* __restrict__ out) {
    const size_t idx = (size_t)blockIdx.x * 256 + threadIdx.x;  // BT/8 threads
    const size_t b  = idx / (NT / 8);
    const size_t t0 = (idx % (NT / 8)) * 8;
    const float* base = wsp + b * NT + t0;
    float v[5][8];
    #pragma unroll
    for (int s = 0; s < 5; ++s) {
        *(float4*)&v[s][0] = *(const float4*)(base + s * BT);
        *(float4*)&v[s][4] = *(const float4*)(base + s * BT + 4);
    }
    float o[40];
    #pragma unroll
    for (int t = 0; t < 8; ++t)
        #pragma unroll
        for (int s = 0; s < 5; ++s) o[t * 5 + s] = v[s][t];
    float4* d = (float4*)(out + (b * NT + t0) * 5);
    const float4* sv = (const float4*)o;
    #pragma unroll
    for (int i = 0; i < 10; ++i) d[i] = sv[i];
}

extern "C" void kernel_launch(void* const* d_in, const int* in_sizes, int n_in,
                              void* d_out, int out_size, void* d_ws, size_t ws_size,
                              hipStream_t stream) {
    const float* inp   = (const float*)d_in[0];
    const float* theta = (const float*)d_in[1];
    float* out = (float*)d_out;
    float* wsp = (float*)d_ws;
    const int use_ws = (wsp != nullptr && ws_size >= 5 * sizeof(float) * BT) ? 1 : 0;
    const int use_p0 = (wsp != nullptr && ws_size >= 9 * sizeof(float) * BT) ? 1 : 0;
    if (use_ws)
        pre_kernel<<<(int)(BT / 4 / 256), 256, 0, stream>>>(inp, theta, out, wsp, use_p0);
    // 32 blocks x 512 threads: block role = blockIdx&3, 8 same-role waves
    // per block -> 1 block/CU, 2 waves/SIMD (HW-interleaved latency hiding).
    prnn_roles<<<32, 512, 0, stream>>>(inp, theta, out, wsp, use_ws, use_p0);
    if (use_ws)
        tx_kernel<<<(int)(BT / 8 / 256), 256, 0, stream>>>(wsp, out);
}

// Round 13
// 561.192 us; speedup vs baseline: 2.7492x; 2.7492x over previous
//
#include <hip/hip_runtime.h>

// PRNNLayer: B=4096 chains x T=2048 steps, 5 states.
// R15: best-of-ledger consolidation, 2 dispatches.
//   - R8 topology: 256 blocks x 64 threads, ONE role per block (max CU
//     spread -- R14 proved concentration is catastrophic: 32 CUs -> 4.4x).
//   - Inline input-only terms (no pre kernel: R12's pre cost ~60-80us +
//     a dispatch gap to save roles only ~45).
//   - R11 pins on every staged buffer (measured -43us on these bodies).
//   - R6 SoA plane stores to ws (direct AoS from desynced roles = 3.7x
//     write amp, R5; barrier pacing = +180us, R7).
//   - R14's tx at 8 timesteps/thread.
// All arithmetic verbatim from verified R8/R11 kernels.

#define NB 4096
#define NT 2048
#define CH 16
#define NCH (NT / CH)         // 128 (roles 0,1)
#define CH23 32
#define BT ((size_t)NB * (size_t)NT)

#define L2E10 14.4269504089f  // 10*log2(e)  (hv(x) = sigmoid(10x))
#define L2E    1.44269504089f

__device__ __forceinline__ float rcpf(float x) { return __builtin_amdgcn_rcpf(x); }
__device__ __forceinline__ float ex2(float a)  { return __builtin_amdgcn_exp2f(a); }
__device__ __forceinline__ float ex2c(float a) { return __builtin_amdgcn_exp2f(fminf(a, 80.0f)); }
__device__ __forceinline__ float clip1e5(float x) {
    return __builtin_amdgcn_fmed3f(x, -100000.0f, 100000.0f);
}
// Pin staged float4s into live VGPRs here (prevents load sinking past this).
__device__ __forceinline__ void pinbuf(const float* d, int n4) {
    const float4* v = (const float4*)d;
    #pragma unroll
    for (int i = 0; i < n4; ++i)
        asm volatile("" :: "v"(v[i].x), "v"(v[i].y), "v"(v[i].z), "v"(v[i].w));
}

// ---------------- Pass 1: role-decomposed serial scans ----------------------
__global__ __launch_bounds__(64, 1)
void prnn_roles(const float* __restrict__ inp, const float* __restrict__ theta,
                float* __restrict__ out, float* __restrict__ wsp, int use_ws) {
    const int lane = threadIdx.x;
    const int role = blockIdx.x & 3;
    const int b = (blockIdx.x >> 2) * 64 + lane;

    const float f_     = theta[0] * 0.1f;
    const float smax_  = theta[1] * 1950.0f;
    const float qmax_  = theta[2] * 50.0f;
    const float ddf_   = theta[3] * 5.0f;
    const float tmin_  = theta[4] * -3.0f;
    const float tmax_  = theta[5] * 3.0f;
    const float Kc_    = theta[6] * 0.5f;
    const float SCmax_ = theta[7] * 1.5f;
    const float spmax_ = theta[8] * 1950.0f;
    const float qpmax_ = theta[9] * 40.0f;
    const float kp     = theta[10];
    const float sgmax_ = theta[11] * 1950.0f;
    const float qgmax_ = theta[12] * 40.0f;
    const float Kl_    = theta[13] * 0.5f;
    const float Kn_    = theta[14] * 0.5f;

    const float inv_smax = rcpf(smax_);
    const float KcDc  = Kc_ * 0.849932f;          // Kc_ * 0.986*0.862
    const float c_sn  = -L2E10 * tmin_;
    const float c_m   =  L2E10 * tmax_;
    const float c_dd  = -ddf_ * tmax_;
    const float c_sc1 =  L2E10 * SCmax_ * 1.4f;
    const float c_sc0 =  L2E10 * SCmax_ * 0.6f;
    const float c_2p  =  L2E10 * spmax_;
    const float c_3s  =  L2E10 * smax_;
    const float c_4s  =  L2E10 * sgmax_;
    const float fE    = f_ * L2E;
    const float c_E2  = -fE * spmax_;
    const float c_E3  = -fE * smax_;
    const float c_E4  = -fE * sgmax_;

    const float* ip = inp + (size_t)b * (NT * 3);
    float*       op = out + (size_t)b * (NT * 5);
    float* wbase = use_ws ? wsp : out;

    auto plane_storeN = [&](float* plane, const float* ob, int off, int n4) {
        float4* d = (float4*)(plane + (size_t)off);
        const float4* s = (const float4*)ob;
        #pragma unroll
        for (int i = 0; i < 8; ++i) { if (i < n4) d[i] = s[i]; }
    };

    if (role == 0) {
        // ---- s0: day/da/kterm/zday inline ----
        float s0 = 0.f;
        float* w0 = wbase + 0 * BT + (size_t)b * NT;
        float bA[CH * 3], bB[CH * 3];
        auto pf = [&](float* d, int c) {
            const float4* s = (const float4*)(ip + (size_t)c * (CH * 3));
            #pragma unroll
            for (int i = 0; i < (CH * 3) / 4; ++i) ((float4*)d)[i] = s[i];
        };
        auto cw = [&](const float* d, int c) {
            float ob[CH];
            #pragma unroll
            for (int i = 0; i < CH; ++i) {
                const float p  = d[i * 3 + 0];
                const float dl = d[i * 3 + 2];
                const float day = rcpf(1.0f + ex2(fmaf(-L2E10, dl, 7.21347520f)));
                const float da  = 1.0f + ex2(fmaf(-L2E10, p, L2E));
                const float lai   = fmaf(0.328f, day, 0.15f);
                const float kcf   = fmaf(0.6f, day, 0.4f);
                const float kterm = KcDc * kcf * lai;
                const float zday  = fmaf(c_sc1, day, c_sc0);
                const float e0  = ex2(-L2E10 * s0);
                const float esc = ex2(fmaf(-L2E10, s0, zday));
                const float d0  = 1.0f + e0;
                const float dsc = 1.0f + esc;
                const float Rp  = rcpf(da * d0 * dsc);
                const float pintc = Rp * fmaf(d0 * esc, kterm, p);
                s0 += clip1e5(pintc);
                ob[i] = s0;
            }
            if (use_ws) plane_storeN(w0, ob, c * CH, CH / 4);
            else {
                #pragma unroll
                for (int i = 0; i < CH; ++i) op[(c * CH + i) * 5 + 0] = ob[i];
            }
        };
        pf(bA, 0);
        for (int c = 0; c < NCH; c += 2) {
            pf(bB, c + 1);
            pinbuf(bA, (CH * 3) / 4);
            cw(bA, c);
            if (c + 2 < NCH) pf(bA, c + 2);
            pinbuf(bB, (CH * 3) / 4);
            cw(bB, c + 1);
        }
    } else if (role == 1) {
        // ---- s1 + s3: pe/psnow/dm inline ----
        float s1 = 0.f, s3 = 0.f;
        float* w1 = wbase + 1 * BT + (size_t)b * NT;
        float* w3 = wbase + 3 * BT + (size_t)b * NT;
        float bA[CH * 3], bB[CH * 3];
        auto pf = [&](float* d, int c) {
            const float4* s = (const float4*)(ip + (size_t)c * (CH * 3));
            #pragma unroll
            for (int i = 0; i < (CH * 3) / 4; ++i) ((float4*)d)[i] = s[i];
        };
        auto cw = [&](const float* d, int c) {
            float ob1[CH], ob3[CH];
            #pragma unroll
            for (int i = 0; i < CH; ++i) {
                const float p  = d[i * 3 + 0];
                const float tm = d[i * 3 + 1];
                const float dl = d[i * 3 + 2];
                const float A1 = tm + 237.3f;
                const float A2 = tm + 273.2f;
                const float qq = rcpf(A1 * A2);
                const float pe = 436.98672f * dl * ex2(24.958624f * tm * (qq * A2)) * (qq * A1);
                const float psnow = rcpf(1.0f + ex2(fmaf(L2E10, tm, c_sn))) * p;
                const float dm = 1.0f + ex2(fmaf(-L2E10, tm, c_m));
                const float prain = p - psnow;
                const float e1 = ex2(-L2E10 * s1);
                const float melt = rcpf(dm * (1.0f + e1))
                                   * fminf(s1, fmaf(ddf_, tm, c_dd));
                const float e3  = ex2(-L2E10 * s3);
                const float e3s = ex2c(fmaf(-L2E10, s3, c_3s));
                const float R3  = rcpf((1.0f + e3) * (1.0f + e3s));
                const float E3  = ex2(fmaf(fE, s3, c_E3));
                const float t_et = pe * fmaf(e3s * s3, inv_smax, 1.0f);
                const float t_qs = qmax_ * fmaf(e3s, E3, 1.0f);
                const float outflux = R3 * (t_et + t_qs + (s3 - smax_));
                const float ds3 = prain + melt - outflux;
                s1 += clip1e5(psnow - melt);
                s3 += clip1e5(ds3);
                ob1[i] = s1;
                ob3[i] = s3;
            }
            if (use_ws) {
                plane_storeN(w1, ob1, c * CH, CH / 4);
                plane_storeN(w3, ob3, c * CH, CH / 4);
            } else {
                #pragma unroll
                for (int i = 0; i < CH; ++i) {
                    op[(c * CH + i) * 5 + 1] = ob1[i];
                    op[(c * CH + i) * 5 + 3] = ob3[i];
                }
            }
        };
        pf(bA, 0);
        for (int c = 0; c < NCH; c += 2) {
            pf(bB, c + 1);
            pinbuf(bA, (CH * 3) / 4);
            cw(bA, c);
            if (c + 2 < NCH) pf(bA, c + 2);
            pinbuf(bB, (CH * 3) / 4);
            cw(bB, c + 1);
        }
    } else if (role == 2) {
        // ---- s2: needs only p ----
        float s2 = 0.f;
        float pA[CH23], pB[CH23];
        float* w2 = wbase + 2 * BT + (size_t)b * NT;
        auto pf = [&](float* P, int c) {
            #pragma unroll
            for (int i = 0; i < CH23; ++i) P[i] = ip[(c * CH23 + i) * 3 + 0];
        };
        auto cw = [&](const float* P, int c) {
            float ob[CH23];
            #pragma unroll
            for (int i = 0; i < CH23; ++i) {
                const float p = P[i];
                const float e2  = ex2(-L2E10 * s2);
                const float e2p = ex2c(fmaf(-L2E10, s2, c_2p));
                const float R2  = rcpf((1.0f + e2) * (1.0f + e2p));
                const float E2  = ex2(fmaf(fE, s2, c_E2));
                const float qpref = R2 * fmaf(e2p * E2, kp * p, qpmax_);
                s2 += clip1e5(qpref);
                ob[i] = s2;
            }
            if (use_ws) plane_storeN(w2, ob, c * CH23, CH23 / 4);
            else {
                #pragma unroll
                for (int i = 0; i < CH23; ++i) op[(c * CH23 + i) * 5 + 2] = ob[i];
            }
        };
        pf(pA, 0);
        for (int c = 0; c < NT / CH23; c += 2) {
            pf(pB, c + 1);
            pinbuf(pA, CH23 / 4);
            cw(pA, c);
            if (c + 2 < NT / CH23) pf(pA, c + 2);
            pinbuf(pB, CH23 / 4);
            cw(pB, c + 1);
        }
    } else {
        // ---- s4: needs only p ----
        float s4 = 0.f;
        float pA[CH23], pB[CH23];
        float* w4 = wbase + 4 * BT + (size_t)b * NT;
        auto pf = [&](float* P, int c) {
            #pragma unroll
            for (int i = 0; i < CH23; ++i) P[i] = ip[(c * CH23 + i) * 3 + 0];
        };
        auto cw = [&](const float* P, int c) {
            float ob[CH23];
            #pragma unroll
            for (int i = 0; i < CH23; ++i) {
                const float p = P[i];
                const float e4  = ex2(-L2E10 * s4);
                const float e4s = ex2c(fmaf(-L2E10, s4, c_4s));
                const float R4  = rcpf((1.0f + e4) * (1.0f + e4s));
                const float E4  = ex2(fmaf(fE, s4, c_E4));
                const float pl  = p * fmaf(p, Kn_, Kl_);
                const float qslow = R4 * fmaf(e4s * E4, pl, qgmax_);
                s4 += clip1e5(qslow);
                ob[i] = s4;
            }
            if (use_ws) plane_storeN(w4, ob, c * CH23, CH23 / 4);
            else {
                #pragma unroll
                for (int i = 0; i < CH23; ++i) op[(c * CH23 + i) * 5 + 4] = ob[i];
            }
        };
        pf(pA, 0);
        for (int c = 0; c < NT / CH23; c += 2) {
            pf(pB, c + 1);
            pinbuf(pA, CH23 / 4);
            cw(pA, c);
            if (c + 2 < NT / CH23) pf(pA, c + 2);
            pinbuf(pB, CH23 / 4);
            cw(pB, c + 1);
        }
    }
}

// ---- Pass 2: SoA planes -> AoS out. 8 timesteps per thread. ----
__global__ __launch_bounds__(256)
void tx_kernel(const float* __restrict__ wsp, float* __restrict__ out) {
    const size_t idx = (size_t)blockIdx.x * 256 + threadIdx.x;  // BT/8 threads
    const size_t b  = idx / (NT / 8);
    const size_t t0 = (idx % (NT / 8)) * 8;
    const float* base = wsp + b * NT + t0;
    float v[5][8];
    #pragma unroll
    for (int s = 0; s < 5; ++s) {
        *(float4*)&v[s][0] = *(const float4*)(base + s * BT);
        *(float4*)&v[s][4] = *(const float4*)(base + s * BT + 4);
    }
    float o[40];
    #pragma unroll
    for (int t = 0; t < 8; ++t)
        #pragma unroll
        for (int s = 0; s < 5; ++s) o[t * 5 + s] = v[s][t];
    float4* d = (float4*)(out + (b * NT + t0) * 5);
    const float4* sv = (const float4*)o;
    #pragma unroll
    for (int i = 0; i < 10; ++i) d[i] = sv[i];
}

extern "C" void kernel_launch(void* const* d_in, const int* in_sizes, int n_in,
                              void* d_out, int out_size, void* d_ws, size_t ws_size,
                              hipStream_t stream) {
    const float* inp   = (const float*)d_in[0];
    const float* theta = (const float*)d_in[1];
    float* out = (float*)d_out;
    float* wsp = (float*)d_ws;
    const int use_ws = (wsp != nullptr && ws_size >= 5 * sizeof(float) * BT) ? 1 : 0;
    prnn_roles<<<4 * (NB / 64), 64, 0, stream>>>(inp, theta, out, wsp, use_ws);
    if (use_ws)
        tx_kernel<<<(int)(BT / 8 / 256), 256, 0, stream>>>(wsp, out);
}